// Round 6
// baseline (140.355 us; speedup 1.0000x reference)
//
#include <hip/hip_runtime.h>

#define D 64

static __device__ __forceinline__ unsigned int bf16r(float f) {
    const unsigned int u = __float_as_uint(f);
    return (u + 0x7fffu + ((u >> 16) & 1u)) >> 16;   // RNE fp32->bf16
}

// ---------------------------------------------------------------------------
// K1: Y = bf16( deg ⊙ (X @ W) ) — LDS-free, scalar-W GEMM.
// Block = 256 thr = 4 waves over the SAME 64 nodes (n0 = blockIdx*64).
// Wave g (=tid>>6) computes feature group 16g..16g+15; lane = node.
// Per q (16 iters): one float4 X-row load per lane + 4 wave-uniform W-row
// reads (s_load, scalar pipe) + 64 v_fma with SGPR multiplicand.
// No LDS, no barriers, no transpose. X rows hit L1 for waves g=1..3.
// Epilogue: 32B bf16 store/lane; the block's 4 g-waves complete each Y
// 128B line inside one L2 -> no partial-line writeback amplification.
// ---------------------------------------------------------------------------
__global__ __launch_bounds__(256, 4)
void gcn_xw_sgpr(const float* __restrict__ X, const float* __restrict__ W,
                 const float* __restrict__ deg, ushort* __restrict__ Y,
                 int n_nodes)
{
    const int lane  = threadIdx.x & 63;
    const int g     = __builtin_amdgcn_readfirstlane((int)(threadIdx.x >> 6));
    const int node  = blockIdx.x * 64 + lane;
    const bool valid = node < n_nodes;

    const float* __restrict__ xrow = X + ((size_t)(valid ? node : 0) << 6);
    const float* __restrict__ wg   = W + 16 * g;      // W[k][16g .. 16g+15]

    float acc[16];
#pragma unroll
    for (int f = 0; f < 16; ++f) acc[f] = 0.f;

#pragma unroll
    for (int q = 0; q < 16; ++q) {
        const float4 xv = *(const float4*)(xrow + 4 * q);
#pragma unroll
        for (int j = 0; j < 4; ++j) {
            // wave-uniform address -> scalar loads (64B row chunk)
            const float* __restrict__ wr = wg + (size_t)(4 * q + j) * D;
            const float xs = (j == 0) ? xv.x : (j == 1) ? xv.y
                           : (j == 2) ? xv.z : xv.w;
#pragma unroll
            for (int f = 0; f < 16; ++f)
                acc[f] = fmaf(xs, wr[f], acc[f]);
        }
    }

    if (valid) {
        const float dn = deg[node];
        unsigned int r[8];
#pragma unroll
        for (int p = 0; p < 8; ++p)
            r[p] = bf16r(acc[2 * p] * dn) | (bf16r(acc[2 * p + 1] * dn) << 16);
        uint4* dst = (uint4*)(Y + ((size_t)node << 6) + 16 * g);
        dst[0] = make_uint4(r[0], r[1], r[2], r[3]);
        dst[1] = make_uint4(r[4], r[5], r[6], r[7]);
    }
}

// ---------------------------------------------------------------------------
// K2: out[i][:] = deg[i] * sum_e Y[col[e]][:]  — 4 nodes per wave, no
// cross-lane ops. lane = (slot s=lane>>4 -> node, chunk f=lane&15 ->
// features [4f,4f+4)). Each lane owns its node's 16 edge indices (4 dwordx4
// loads), 16 independent dwordx2 row loads (each instr = 4 full 128B rows),
// accumulates 4 fp32, stores one float4 (1KB/instr wave store).
// ~205 MB random full-line gather from L2/LLC-resident Y.
// ---------------------------------------------------------------------------
__global__ __launch_bounds__(256, 4)
void gcn_gather4(const ushort* __restrict__ Y, const int* __restrict__ rp,
                 const int* __restrict__ col, const float* __restrict__ deg,
                 float* __restrict__ out, int n_nodes)
{
    const int lane   = threadIdx.x & 63;
    const int s      = lane >> 4;
    const int f      = lane & 15;
    const int gwave  = (int)((blockIdx.x * blockDim.x + threadIdx.x) >> 6);
    const int nwaves = (int)((gridDim.x * blockDim.x) >> 6);
    const int ngroups = (n_nodes + 3) >> 2;

    for (int g = gwave; g < ngroups; g += nwaves) {
        const int  n     = g * 4 + s;
        const bool valid = (n < n_nodes);
        const int  rpn   = valid ? rp[n]     : 0;
        const int  rpe   = valid ? rp[n + 1] : 0;
        const int  dcnt  = rpe - rpn;

        const bool ok = !valid || (dcnt == 16 && (rpn & 3) == 0);
        if (__ballot(ok) == ~0ull) {
            int idx[16];
            *(int4*)(idx + 0)  = *(const int4*)(col + rpn + 0);
            *(int4*)(idx + 4)  = *(const int4*)(col + rpn + 4);
            *(int4*)(idx + 8)  = *(const int4*)(col + rpn + 8);
            *(int4*)(idx + 12) = *(const int4*)(col + rpn + 12);

            float a0 = 0.f, a1 = 0.f, a2 = 0.f, a3 = 0.f;
#pragma unroll
            for (int j = 0; j < 16; ++j) {
                const uint2 u = *(const uint2*)(Y + ((size_t)idx[j] << 6) + (f << 2));
                a0 += __uint_as_float(u.x << 16);
                a1 += __uint_as_float(u.x & 0xffff0000u);
                a2 += __uint_as_float(u.y << 16);
                a3 += __uint_as_float(u.y & 0xffff0000u);
            }
            if (valid) {
                const float dn = deg[n];
                float4 v;
                v.x = a0 * dn; v.y = a1 * dn; v.z = a2 * dn; v.w = a3 * dn;
                *(float4*)(out + (size_t)n * D + f * 4) = v;
            }
        } else if (valid) {
            float a0 = 0.f, a1 = 0.f, a2 = 0.f, a3 = 0.f;
            for (int e = rpn; e < rpe; ++e) {
                const int sj = col[e];
                const uint2 u = *(const uint2*)(Y + ((size_t)sj << 6) + (f << 2));
                a0 += __uint_as_float(u.x << 16);
                a1 += __uint_as_float(u.x & 0xffff0000u);
                a2 += __uint_as_float(u.y << 16);
                a3 += __uint_as_float(u.y & 0xffff0000u);
            }
            const float dn = deg[n];
            float4 v;
            v.x = a0 * dn; v.y = a1 * dn; v.z = a2 * dn; v.w = a3 * dn;
            *(float4*)(out + (size_t)n * D + f * 4) = v;
        }
    }
}

// ---------------------------------------------------------------------------
// Fallback (ws too small): fused fp32 kernel.
// ---------------------------------------------------------------------------
static __device__ __forceinline__ float bcast_f(float v, int l) {
    return __uint_as_float(__builtin_amdgcn_readlane(__float_as_uint(v), l));
}

__global__ __launch_bounds__(256, 4)
void gcn_fused_kernel(const float* __restrict__ X, const float* __restrict__ W,
                      const int* __restrict__ rp, const int* __restrict__ col,
                      const float* __restrict__ deg, float* __restrict__ out,
                      int n_nodes)
{
    const int lane   = threadIdx.x & 63;
    const int gwave  = (int)((blockIdx.x * blockDim.x + threadIdx.x) >> 6);
    const int nwaves = (int)((gridDim.x * blockDim.x) >> 6);

    for (int node = gwave; node < n_nodes; node += nwaves) {
        const int start = rp[node];
        const int end   = rp[node + 1];
        const float di  = deg[node];
        float h = 0.f;

        for (int e0 = start; e0 < end; e0 += 64) {
            const int cnt = min(64, end - e0);
            int   s_  = (lane < cnt) ? col[e0 + lane] : 0;
            float nm_ = (lane < cnt) ? di * deg[s_] : 0.f;
            for (int j = 0; j < cnt; ++j) {
                const int   sj = __builtin_amdgcn_readlane(s_, j);
                const float nj = bcast_f(nm_, j);
                h = fmaf(nj, X[(size_t)sj * D + lane], h);
            }
        }

        float c0 = 0.f, c1 = 0.f, c2 = 0.f, c3 = 0.f;
#pragma unroll
        for (int l = 0; l < D; l += 4) {
            c0 = fmaf(bcast_f(h, l + 0), W[(l + 0) * D + lane], c0);
            c1 = fmaf(bcast_f(h, l + 1), W[(l + 1) * D + lane], c1);
            c2 = fmaf(bcast_f(h, l + 2), W[(l + 2) * D + lane], c2);
            c3 = fmaf(bcast_f(h, l + 3), W[(l + 3) * D + lane], c3);
        }
        out[(size_t)node * D + lane] = (c0 + c1) + (c2 + c3);
    }
}

extern "C" void kernel_launch(void* const* d_in, const int* in_sizes, int n_in,
                              void* d_out, int out_size, void* d_ws, size_t ws_size,
                              hipStream_t stream) {
    const float* X   = (const float*)d_in[0];
    const float* W   = (const float*)d_in[1];
    const int*   rp  = (const int*)d_in[2];
    const int*   col = (const int*)d_in[3];
    const float* deg = (const float*)d_in[4];
    float* out = (float*)d_out;

    const int n_nodes = in_sizes[4];   // degrees: one per node
    const size_t y_bytes = (size_t)n_nodes * D * sizeof(ushort);

    if (ws_size >= y_bytes) {
        ushort* Y = (ushort*)d_ws;
        const int k1_blocks = (n_nodes + 63) / 64;
        gcn_xw_sgpr<<<k1_blocks, 256, 0, stream>>>(X, W, deg, Y, n_nodes);
        gcn_gather4<<<2048, 256, 0, stream>>>(Y, rp, col, deg, out, n_nodes);
    } else {
        gcn_fused_kernel<<<1024, 256, 0, stream>>>(X, W, rp, col, deg, out, n_nodes);
    }
}

// Round 7
// 120.397 us; speedup vs baseline: 1.1658x; 1.1658x over previous
//
#include <hip/hip_runtime.h>
#include <hip/hip_bf16.h>

#define D 64

typedef __attribute__((ext_vector_type(8))) short bf16x8;
typedef __attribute__((ext_vector_type(4))) float f32x4;

union Frag {
    bf16x8 v;
    __hip_bfloat162 h[4];
};

static __device__ __forceinline__ unsigned int bf16r(float f) {
    const unsigned int u = __float_as_uint(f);
    return (u + 0x7fffu + ((u >> 16) & 1u)) >> 16;   // RNE fp32->bf16
}

// ---------------------------------------------------------------------------
// K1: Y = bf16( deg ⊙ (X @ W) ) — MFMA (16x16x32 bf16), no LDS, no barriers.
// Each wave owns strips of 16 nodes (grid-stride). W (64x64, 16KB, L1/L2
// resident) is pre-converted to bf16 into 8 register B-fragments
// (4 feat-tiles x 2 k-steps, 32 VGPRs). Per strip: 4 float4 X loads/lane in
// A-fragment layout (A[m=lane&15][k=quad*8+j]), cvt to bf16, 8 MFMA into 4
// f32x4 accumulators, scale by deg (C layout row=quad*4+reg, col=lane&15),
// round to bf16, 16 ushort stores. HBM-bound on X (25.6 MB).
// ---------------------------------------------------------------------------
__global__ __launch_bounds__(256, 4)
void gcn_xw_mfma(const float* __restrict__ X, const float* __restrict__ W,
                 const float* __restrict__ deg, ushort* __restrict__ Y,
                 int n_nodes, int nstrips)
{
    const int lane = threadIdx.x & 63;
    const int q    = lane >> 4;        // quad 0..3
    const int r    = lane & 15;        // row-in-frag / col-in-frag
    const int wid  = blockIdx.x * 4 + (threadIdx.x >> 6);
    const int nw   = gridDim.x * 4;

    // ---- B fragments: bf[ft][s] holds W[32s + q*8 + j][16*ft + r], j=0..7
    Frag bf[4][2];
#pragma unroll
    for (int ft = 0; ft < 4; ++ft) {
        const int c = 16 * ft + r;
#pragma unroll
        for (int s = 0; s < 2; ++s) {
            const int k0 = 32 * s + q * 8;
#pragma unroll
            for (int p = 0; p < 4; ++p) {
                const float a = W[(size_t)(k0 + 2 * p)     * D + c];
                const float b = W[(size_t)(k0 + 2 * p + 1) * D + c];
                bf[ft][s].h[p] = __float22bfloat162_rn(make_float2(a, b));
            }
        }
    }

    for (int strip = wid; strip < nstrips; strip += nw) {
        const int n0 = strip * 16;
        const bool full = (n0 + 16 <= n_nodes);

        // ---- A fragments: af[s] holds X[n0 + r][32s + q*8 + j]
        Frag af[2];
        {
            const int row  = full ? (n0 + r) : min(n0 + r, n_nodes - 1);
            const float* __restrict__ xr = X + ((size_t)row << 6);
#pragma unroll
            for (int s = 0; s < 2; ++s) {
                const float4 f0 = *(const float4*)(xr + 32 * s + q * 8);
                const float4 f1 = *(const float4*)(xr + 32 * s + q * 8 + 4);
                af[s].h[0] = __float22bfloat162_rn(make_float2(f0.x, f0.y));
                af[s].h[1] = __float22bfloat162_rn(make_float2(f0.z, f0.w));
                af[s].h[2] = __float22bfloat162_rn(make_float2(f1.x, f1.y));
                af[s].h[3] = __float22bfloat162_rn(make_float2(f1.z, f1.w));
            }
        }

        // ---- 8 MFMA: acc[ft] = sum_s A_s * B[ft][s]
        f32x4 acc[4];
#pragma unroll
        for (int ft = 0; ft < 4; ++ft) {
            f32x4 z = {0.f, 0.f, 0.f, 0.f};
            acc[ft] = z;
        }
#pragma unroll
        for (int s = 0; s < 2; ++s)
#pragma unroll
            for (int ft = 0; ft < 4; ++ft)
                acc[ft] = __builtin_amdgcn_mfma_f32_16x16x32_bf16(
                              af[s].v, bf[ft][s].v, acc[ft], 0, 0, 0);

        // ---- epilogue: rows q*4+i, col r (+16*ft) ----
        if (full) {
            const float4 dn = *(const float4*)(deg + n0 + 4 * q);
#pragma unroll
            for (int i = 0; i < 4; ++i) {
                const int   node = n0 + 4 * q + i;
                const float d    = (i == 0) ? dn.x : (i == 1) ? dn.y
                                 : (i == 2) ? dn.z : dn.w;
                ushort* yr = Y + ((size_t)node << 6) + r;
#pragma unroll
                for (int ft = 0; ft < 4; ++ft)
                    yr[16 * ft] = (ushort)bf16r(acc[ft][i] * d);
            }
        } else {
#pragma unroll
            for (int i = 0; i < 4; ++i) {
                const int node = n0 + 4 * q + i;
                if (node < n_nodes) {
                    const float d = deg[node];
                    ushort* yr = Y + ((size_t)node << 6) + r;
#pragma unroll
                    for (int ft = 0; ft < 4; ++ft)
                        yr[16 * ft] = (ushort)bf16r(acc[ft][i] * d);
                }
            }
        }
    }
}

// ---------------------------------------------------------------------------
// K2: out[i][:] = deg[i] * sum_e Y[col[e]][:]  — 4 nodes per wave, no
// cross-lane ops. lane = (slot s=lane>>4 -> node, chunk f=lane&15 ->
// features [4f,4f+4)). Each lane owns its node's 16 edge indices (4 dwordx4
// loads), 16 independent dwordx2 row loads, accumulates 4 fp32, stores one
// float4. ~205 MB random full-line gather from L2/LLC-resident Y (floor).
// ---------------------------------------------------------------------------
__global__ __launch_bounds__(256, 4)
void gcn_gather4(const ushort* __restrict__ Y, const int* __restrict__ rp,
                 const int* __restrict__ col, const float* __restrict__ deg,
                 float* __restrict__ out, int n_nodes)
{
    const int lane   = threadIdx.x & 63;
    const int s      = lane >> 4;
    const int f      = lane & 15;
    const int gwave  = (int)((blockIdx.x * blockDim.x + threadIdx.x) >> 6);
    const int nwaves = (int)((gridDim.x * blockDim.x) >> 6);
    const int ngroups = (n_nodes + 3) >> 2;

    for (int g = gwave; g < ngroups; g += nwaves) {
        const int  n     = g * 4 + s;
        const bool valid = (n < n_nodes);
        const int  rpn   = valid ? rp[n]     : 0;
        const int  rpe   = valid ? rp[n + 1] : 0;
        const int  dcnt  = rpe - rpn;

        const bool ok = !valid || (dcnt == 16 && (rpn & 3) == 0);
        if (__ballot(ok) == ~0ull) {
            int idx[16];
            *(int4*)(idx + 0)  = *(const int4*)(col + rpn + 0);
            *(int4*)(idx + 4)  = *(const int4*)(col + rpn + 4);
            *(int4*)(idx + 8)  = *(const int4*)(col + rpn + 8);
            *(int4*)(idx + 12) = *(const int4*)(col + rpn + 12);

            float a0 = 0.f, a1 = 0.f, a2 = 0.f, a3 = 0.f;
#pragma unroll
            for (int j = 0; j < 16; ++j) {
                const uint2 u = *(const uint2*)(Y + ((size_t)idx[j] << 6) + (f << 2));
                a0 += __uint_as_float(u.x << 16);
                a1 += __uint_as_float(u.x & 0xffff0000u);
                a2 += __uint_as_float(u.y << 16);
                a3 += __uint_as_float(u.y & 0xffff0000u);
            }
            if (valid) {
                const float dn = deg[n];
                float4 v;
                v.x = a0 * dn; v.y = a1 * dn; v.z = a2 * dn; v.w = a3 * dn;
                *(float4*)(out + (size_t)n * D + f * 4) = v;
            }
        } else if (valid) {
            float a0 = 0.f, a1 = 0.f, a2 = 0.f, a3 = 0.f;
            for (int e = rpn; e < rpe; ++e) {
                const int sj = col[e];
                const uint2 u = *(const uint2*)(Y + ((size_t)sj << 6) + (f << 2));
                a0 += __uint_as_float(u.x << 16);
                a1 += __uint_as_float(u.x & 0xffff0000u);
                a2 += __uint_as_float(u.y << 16);
                a3 += __uint_as_float(u.y & 0xffff0000u);
            }
            const float dn = deg[n];
            float4 v;
            v.x = a0 * dn; v.y = a1 * dn; v.z = a2 * dn; v.w = a3 * dn;
            *(float4*)(out + (size_t)n * D + f * 4) = v;
        }
    }
}

// ---------------------------------------------------------------------------
// Fallback (ws too small): fused fp32 kernel.
// ---------------------------------------------------------------------------
static __device__ __forceinline__ float bcast_f(float v, int l) {
    return __uint_as_float(__builtin_amdgcn_readlane(__float_as_uint(v), l));
}

__global__ __launch_bounds__(256, 4)
void gcn_fused_kernel(const float* __restrict__ X, const float* __restrict__ W,
                      const int* __restrict__ rp, const int* __restrict__ col,
                      const float* __restrict__ deg, float* __restrict__ out,
                      int n_nodes)
{
    const int lane   = threadIdx.x & 63;
    const int gwave  = (int)((blockIdx.x * blockDim.x + threadIdx.x) >> 6);
    const int nwaves = (int)((gridDim.x * blockDim.x) >> 6);

    for (int node = gwave; node < n_nodes; node += nwaves) {
        const int start = rp[node];
        const int end   = rp[node + 1];
        const float di  = deg[node];
        float h = 0.f;

        for (int e0 = start; e0 < end; e0 += 64) {
            const int cnt = min(64, end - e0);
            int   s_  = (lane < cnt) ? col[e0 + lane] : 0;
            float nm_ = (lane < cnt) ? di * deg[s_] : 0.f;
            for (int j = 0; j < cnt; ++j) {
                const int   sj = __builtin_amdgcn_readlane(s_, j);
                const float nj = bcast_f(nm_, j);
                h = fmaf(nj, X[(size_t)sj * D + lane], h);
            }
        }

        float c0 = 0.f, c1 = 0.f, c2 = 0.f, c3 = 0.f;
#pragma unroll
        for (int l = 0; l < D; l += 4) {
            c0 = fmaf(bcast_f(h, l + 0), W[(l + 0) * D + lane], c0);
            c1 = fmaf(bcast_f(h, l + 1), W[(l + 1) * D + lane], c1);
            c2 = fmaf(bcast_f(h, l + 2), W[(l + 2) * D + lane], c2);
            c3 = fmaf(bcast_f(h, l + 3), W[(l + 3) * D + lane], c3);
        }
        out[(size_t)node * D + lane] = (c0 + c1) + (c2 + c3);
    }
}

extern "C" void kernel_launch(void* const* d_in, const int* in_sizes, int n_in,
                              void* d_out, int out_size, void* d_ws, size_t ws_size,
                              hipStream_t stream) {
    const float* X   = (const float*)d_in[0];
    const float* W   = (const float*)d_in[1];
    const int*   rp  = (const int*)d_in[2];
    const int*   col = (const int*)d_in[3];
    const float* deg = (const float*)d_in[4];
    float* out = (float*)d_out;

    const int n_nodes = in_sizes[4];   // degrees: one per node
    const size_t y_bytes = (size_t)n_nodes * D * sizeof(ushort);

    if (ws_size >= y_bytes) {
        ushort* Y = (ushort*)d_ws;
        const int nstrips = (n_nodes + 15) / 16;
        gcn_xw_mfma<<<256, 256, 0, stream>>>(X, W, deg, Y, n_nodes, nstrips);
        gcn_gather4<<<2048, 256, 0, stream>>>(Y, rp, col, deg, out, n_nodes);
    } else {
        gcn_fused_kernel<<<1024, 256, 0, stream>>>(X, W, rp, col, deg, out, n_nodes);
    }
}

// Round 8
// 117.535 us; speedup vs baseline: 1.1942x; 1.0244x over previous
//
#include <hip/hip_runtime.h>
#include <hip/hip_bf16.h>

#define D 64

typedef __attribute__((ext_vector_type(8))) short bf16x8;
typedef __attribute__((ext_vector_type(4))) float f32x4;

union Frag {
    bf16x8 v;
    __hip_bfloat162 h[4];
};

static __device__ __forceinline__ unsigned int bf16r(float f) {
    const unsigned int u = __float_as_uint(f);
    return (u + 0x7fffu + ((u >> 16) & 1u)) >> 16;   // RNE fp32->bf16
}

// ---------------------------------------------------------------------------
// K1: Y = bf16( deg ⊙ (X @ W) ) — MFMA (16x16x32 bf16), no LDS, no barriers.
// Grid = 768 blocks (3/CU, 3 waves/SIMD — round-7 ran 1 wave/SIMD and was
// latency-bound at 17.7 µs). Each wave owns ~2 strips of 16 nodes
// (grid-stride). W (16KB, L1/L2-resident) pre-converted to 8 register
// B-fragments. Per strip: 4 float4 X loads/lane in A-fragment layout
// (A[m=lane&15][k=quad*8+j]), cvt, 8 MFMA, scale by deg (C layout
// row=quad*4+reg, col=lane&15), round, 16 ushort stores.
// ---------------------------------------------------------------------------
__global__ __launch_bounds__(256, 4)
void gcn_xw_mfma(const float* __restrict__ X, const float* __restrict__ W,
                 const float* __restrict__ deg, ushort* __restrict__ Y,
                 int n_nodes, int nstrips)
{
    const int lane = threadIdx.x & 63;
    const int q    = lane >> 4;        // quad 0..3
    const int r    = lane & 15;        // row-in-frag / col-in-frag
    const int wid  = blockIdx.x * 4 + (threadIdx.x >> 6);
    const int nw   = gridDim.x * 4;

    // ---- B fragments: bf[ft][s] holds W[32s + q*8 + j][16*ft + r], j=0..7
    Frag bf[4][2];
#pragma unroll
    for (int ft = 0; ft < 4; ++ft) {
        const int c = 16 * ft + r;
#pragma unroll
        for (int s = 0; s < 2; ++s) {
            const int k0 = 32 * s + q * 8;
#pragma unroll
            for (int p = 0; p < 4; ++p) {
                const float a = W[(size_t)(k0 + 2 * p)     * D + c];
                const float b = W[(size_t)(k0 + 2 * p + 1) * D + c];
                bf[ft][s].h[p] = __float22bfloat162_rn(make_float2(a, b));
            }
        }
    }

    for (int strip = wid; strip < nstrips; strip += nw) {
        const int n0 = strip * 16;
        const bool full = (n0 + 16 <= n_nodes);

        // ---- A fragments: af[s] holds X[n0 + r][32s + q*8 + j]
        Frag af[2];
        {
            const int row  = full ? (n0 + r) : min(n0 + r, n_nodes - 1);
            const float* __restrict__ xr = X + ((size_t)row << 6);
#pragma unroll
            for (int s = 0; s < 2; ++s) {
                const float4 f0 = *(const float4*)(xr + 32 * s + q * 8);
                const float4 f1 = *(const float4*)(xr + 32 * s + q * 8 + 4);
                af[s].h[0] = __float22bfloat162_rn(make_float2(f0.x, f0.y));
                af[s].h[1] = __float22bfloat162_rn(make_float2(f0.z, f0.w));
                af[s].h[2] = __float22bfloat162_rn(make_float2(f1.x, f1.y));
                af[s].h[3] = __float22bfloat162_rn(make_float2(f1.z, f1.w));
            }
        }

        // ---- 8 MFMA: acc[ft] = sum_s A_s * B[ft][s]
        f32x4 acc[4];
#pragma unroll
        for (int ft = 0; ft < 4; ++ft) {
            f32x4 z = {0.f, 0.f, 0.f, 0.f};
            acc[ft] = z;
        }
#pragma unroll
        for (int s = 0; s < 2; ++s)
#pragma unroll
            for (int ft = 0; ft < 4; ++ft)
                acc[ft] = __builtin_amdgcn_mfma_f32_16x16x32_bf16(
                              af[s].v, bf[ft][s].v, acc[ft], 0, 0, 0);

        // ---- epilogue: rows q*4+i, col r (+16*ft) ----
        if (full) {
            const float4 dn = *(const float4*)(deg + n0 + 4 * q);
#pragma unroll
            for (int i = 0; i < 4; ++i) {
                const int   node = n0 + 4 * q + i;
                const float d    = (i == 0) ? dn.x : (i == 1) ? dn.y
                                 : (i == 2) ? dn.z : dn.w;
                ushort* yr = Y + ((size_t)node << 6) + r;
#pragma unroll
                for (int ft = 0; ft < 4; ++ft)
                    yr[16 * ft] = (ushort)bf16r(acc[ft][i] * d);
            }
        } else {
#pragma unroll
            for (int i = 0; i < 4; ++i) {
                const int node = n0 + 4 * q + i;
                if (node < n_nodes) {
                    const float d = deg[node];
                    ushort* yr = Y + ((size_t)node << 6) + r;
#pragma unroll
                    for (int ft = 0; ft < 4; ++ft)
                        yr[16 * ft] = (ushort)bf16r(acc[ft][i] * d);
                }
            }
        }
    }
}

// ---------------------------------------------------------------------------
// K2: out[i][:] = deg[i] * sum_e Y[col[e]][:]  — 4 nodes per wave, no
// cross-lane ops. lane = (slot s=lane>>4 -> node, chunk f=lane&15 ->
// features [4f,4f+4)). Each lane owns its node's 16 edge indices (4 dwordx4
// loads), 16 independent dwordx2 row loads, accumulates 4 fp32, stores one
// float4. ~205 MB random full-line gather (each 128B line = one fully-used
// Y row) from L2/LLC — compulsory-traffic floor.
// ---------------------------------------------------------------------------
__global__ __launch_bounds__(256, 4)
void gcn_gather4(const ushort* __restrict__ Y, const int* __restrict__ rp,
                 const int* __restrict__ col, const float* __restrict__ deg,
                 float* __restrict__ out, int n_nodes)
{
    const int lane   = threadIdx.x & 63;
    const int s      = lane >> 4;
    const int f      = lane & 15;
    const int gwave  = (int)((blockIdx.x * blockDim.x + threadIdx.x) >> 6);
    const int nwaves = (int)((gridDim.x * blockDim.x) >> 6);
    const int ngroups = (n_nodes + 3) >> 2;

    for (int g = gwave; g < ngroups; g += nwaves) {
        const int  n     = g * 4 + s;
        const bool valid = (n < n_nodes);
        const int  rpn   = valid ? rp[n]     : 0;
        const int  rpe   = valid ? rp[n + 1] : 0;
        const int  dcnt  = rpe - rpn;

        const bool ok = !valid || (dcnt == 16 && (rpn & 3) == 0);
        if (__ballot(ok) == ~0ull) {
            int idx[16];
            *(int4*)(idx + 0)  = *(const int4*)(col + rpn + 0);
            *(int4*)(idx + 4)  = *(const int4*)(col + rpn + 4);
            *(int4*)(idx + 8)  = *(const int4*)(col + rpn + 8);
            *(int4*)(idx + 12) = *(const int4*)(col + rpn + 12);

            float a0 = 0.f, a1 = 0.f, a2 = 0.f, a3 = 0.f;
#pragma unroll
            for (int j = 0; j < 16; ++j) {
                const uint2 u = *(const uint2*)(Y + ((size_t)idx[j] << 6) + (f << 2));
                a0 += __uint_as_float(u.x << 16);
                a1 += __uint_as_float(u.x & 0xffff0000u);
                a2 += __uint_as_float(u.y << 16);
                a3 += __uint_as_float(u.y & 0xffff0000u);
            }
            if (valid) {
                const float dn = deg[n];
                float4 v;
                v.x = a0 * dn; v.y = a1 * dn; v.z = a2 * dn; v.w = a3 * dn;
                *(float4*)(out + (size_t)n * D + f * 4) = v;
            }
        } else if (valid) {
            float a0 = 0.f, a1 = 0.f, a2 = 0.f, a3 = 0.f;
            for (int e = rpn; e < rpe; ++e) {
                const int sj = col[e];
                const uint2 u = *(const uint2*)(Y + ((size_t)sj << 6) + (f << 2));
                a0 += __uint_as_float(u.x << 16);
                a1 += __uint_as_float(u.x & 0xffff0000u);
                a2 += __uint_as_float(u.y << 16);
                a3 += __uint_as_float(u.y & 0xffff0000u);
            }
            const float dn = deg[n];
            float4 v;
            v.x = a0 * dn; v.y = a1 * dn; v.z = a2 * dn; v.w = a3 * dn;
            *(float4*)(out + (size_t)n * D + f * 4) = v;
        }
    }
}

// ---------------------------------------------------------------------------
// Fallback (ws too small): fused fp32 kernel.
// ---------------------------------------------------------------------------
static __device__ __forceinline__ float bcast_f(float v, int l) {
    return __uint_as_float(__builtin_amdgcn_readlane(__float_as_uint(v), l));
}

__global__ __launch_bounds__(256, 4)
void gcn_fused_kernel(const float* __restrict__ X, const float* __restrict__ W,
                      const int* __restrict__ rp, const int* __restrict__ col,
                      const float* __restrict__ deg, float* __restrict__ out,
                      int n_nodes)
{
    const int lane   = threadIdx.x & 63;
    const int gwave  = (int)((blockIdx.x * blockDim.x + threadIdx.x) >> 6);
    const int nwaves = (int)((gridDim.x * blockDim.x) >> 6);

    for (int node = gwave; node < n_nodes; node += nwaves) {
        const int start = rp[node];
        const int end   = rp[node + 1];
        const float di  = deg[node];
        float h = 0.f;

        for (int e0 = start; e0 < end; e0 += 64) {
            const int cnt = min(64, end - e0);
            int   s_  = (lane < cnt) ? col[e0 + lane] : 0;
            float nm_ = (lane < cnt) ? di * deg[s_] : 0.f;
            for (int j = 0; j < cnt; ++j) {
                const int   sj = __builtin_amdgcn_readlane(s_, j);
                const float nj = bcast_f(nm_, j);
                h = fmaf(nj, X[(size_t)sj * D + lane], h);
            }
        }

        float c0 = 0.f, c1 = 0.f, c2 = 0.f, c3 = 0.f;
#pragma unroll
        for (int l = 0; l < D; l += 4) {
            c0 = fmaf(bcast_f(h, l + 0), W[(l + 0) * D + lane], c0);
            c1 = fmaf(bcast_f(h, l + 1), W[(l + 1) * D + lane], c1);
            c2 = fmaf(bcast_f(h, l + 2), W[(l + 2) * D + lane], c2);
            c3 = fmaf(bcast_f(h, l + 3), W[(l + 3) * D + lane], c3);
        }
        out[(size_t)node * D + lane] = (c0 + c1) + (c2 + c3);
    }
}

extern "C" void kernel_launch(void* const* d_in, const int* in_sizes, int n_in,
                              void* d_out, int out_size, void* d_ws, size_t ws_size,
                              hipStream_t stream) {
    const float* X   = (const float*)d_in[0];
    const float* W   = (const float*)d_in[1];
    const int*   rp  = (const int*)d_in[2];
    const int*   col = (const int*)d_in[3];
    const float* deg = (const float*)d_in[4];
    float* out = (float*)d_out;

    const int n_nodes = in_sizes[4];   // degrees: one per node
    const size_t y_bytes = (size_t)n_nodes * D * sizeof(ushort);

    if (ws_size >= y_bytes) {
        ushort* Y = (ushort*)d_ws;
        const int nstrips = (n_nodes + 15) / 16;
        // 768 blocks = 3/CU = 3 waves/SIMD (round-7's 256 blocks ran
        // 1 wave/SIMD and was fully latency-exposed); ~2 strips/wave keeps
        // the per-wave B-fragment setup amortized.
        gcn_xw_mfma<<<768, 256, 0, stream>>>(X, W, deg, Y, n_nodes, nstrips);
        gcn_gather4<<<2048, 256, 0, stream>>>(Y, rp, col, deg, out, n_nodes);
    } else {
        gcn_fused_kernel<<<1024, 256, 0, stream>>>(X, W, rp, col, deg, out, n_nodes);
    }
}

// Round 10
// 116.843 us; speedup vs baseline: 1.2012x; 1.0059x over previous
//
#include <hip/hip_runtime.h>
#include <hip/hip_bf16.h>

#define D 64

typedef __attribute__((ext_vector_type(8))) short bf16x8;
typedef __attribute__((ext_vector_type(4))) float f32x4;

// POD fragment: only trivially-copyable members (bf16 pairs kept as uint).
union Frag {
    bf16x8 v;
    unsigned int p[4];   // each = two packed bf16
    ushort u[8];
};

static __device__ __forceinline__ unsigned int bf16r(float f) {
    const unsigned int u = __float_as_uint(f);
    return (u + 0x7fffu + ((u >> 16) & 1u)) >> 16;   // RNE fp32->bf16
}

static __device__ __forceinline__ unsigned int pack2(float a, float b) {
    return bf16r(a) | (bf16r(b) << 16);              // [lo=a, hi=b]
}

// ---------------------------------------------------------------------------
// K1: Y = bf16( deg ⊙ (X @ W) ) — MFMA (16x16x32 bf16).
// W staged ONCE per block into LDS (coalesced float4 loads, RNE cvt,
// transposed Wt[c][k] bf16, stride 72 ushort = 144 B so every fragment
// slice is 16B-aligned), one barrier, then each wave builds its 8
// B-fragments with 8x ds_read_b128 — replacing round-8's 64 scattered 4B
// vector loads + 64 cvts PER WAVE (setup was ~1/3 of K1 at ~2 strips/wave).
// Strip loop: 4 float4 X loads/lane in A-fragment layout
// (A[m=lane&15][k=8q+j]), cvt, 8 MFMA, deg-scale (C: row=4q+i, col=r),
// round, 16 ushort stores. Grid 768 = 3 blocks/CU.
// ---------------------------------------------------------------------------
__global__ __launch_bounds__(256, 4)
void gcn_xw_mfma(const float* __restrict__ X, const float* __restrict__ W,
                 const float* __restrict__ deg, ushort* __restrict__ Y,
                 int n_nodes, int nstrips)
{
    __shared__ ushort Wt[64][72];      // Wt[c][k] = bf16(W[k][c])

    const int t    = threadIdx.x;
    const int lane = t & 63;
    const int q    = lane >> 4;        // quad 0..3
    const int r    = lane & 15;        // row-in-frag / col-in-frag

    // ---- cooperative W -> LDS (transposed, bf16); fully coalesced ----
    {
        const float4* __restrict__ W4 = (const float4*)W;
#pragma unroll
        for (int m = 0; m < 4; ++m) {
            const float4 v = W4[t + 256 * m];
            const int idx0 = 4 * (t + 256 * m);   // flat element idx of v.x
            const int k = idx0 >> 6;              // W row
            const int c = idx0 & 63;              // W col of v.x
            Wt[c + 0][k] = (ushort)bf16r(v.x);
            Wt[c + 1][k] = (ushort)bf16r(v.y);
            Wt[c + 2][k] = (ushort)bf16r(v.z);
            Wt[c + 3][k] = (ushort)bf16r(v.w);
        }
    }
    __syncthreads();

    // ---- B fragments: bf[ft][s].u[j] = bf16(W[32s+8q+j][16ft+r]) ----
    Frag bf[4][2];
#pragma unroll
    for (int ft = 0; ft < 4; ++ft)
#pragma unroll
        for (int s = 0; s < 2; ++s)
            bf[ft][s].v = *(const bf16x8*)&Wt[16 * ft + r][32 * s + 8 * q];

    const int wid = blockIdx.x * 4 + (t >> 6);
    const int nw  = gridDim.x * 4;

    for (int strip = wid; strip < nstrips; strip += nw) {
        const int n0 = strip * 16;
        const bool full = (n0 + 16 <= n_nodes);

        // ---- A fragments: af[s] holds X[n0 + r][32s + q*8 + j] ----
        Frag af[2];
        {
            const int row  = full ? (n0 + r) : min(n0 + r, n_nodes - 1);
            const float* __restrict__ xr = X + ((size_t)row << 6);
#pragma unroll
            for (int s = 0; s < 2; ++s) {
                const float4 f0 = *(const float4*)(xr + 32 * s + q * 8);
                const float4 f1 = *(const float4*)(xr + 32 * s + q * 8 + 4);
                af[s].p[0] = pack2(f0.x, f0.y);
                af[s].p[1] = pack2(f0.z, f0.w);
                af[s].p[2] = pack2(f1.x, f1.y);
                af[s].p[3] = pack2(f1.z, f1.w);
            }
        }

        // ---- 8 MFMA: acc[ft] = sum_s A_s * B[ft][s] ----
        f32x4 acc[4];
#pragma unroll
        for (int ft = 0; ft < 4; ++ft) {
            f32x4 z = {0.f, 0.f, 0.f, 0.f};
            acc[ft] = z;
        }
#pragma unroll
        for (int s = 0; s < 2; ++s)
#pragma unroll
            for (int ft = 0; ft < 4; ++ft)
                acc[ft] = __builtin_amdgcn_mfma_f32_16x16x32_bf16(
                              af[s].v, bf[ft][s].v, acc[ft], 0, 0, 0);

        // ---- epilogue: rows q*4+i, col r (+16*ft) ----
        if (full) {
            const float4 dn = *(const float4*)(deg + n0 + 4 * q);
#pragma unroll
            for (int i = 0; i < 4; ++i) {
                const int   node = n0 + 4 * q + i;
                const float d    = (i == 0) ? dn.x : (i == 1) ? dn.y
                                 : (i == 2) ? dn.z : dn.w;
                ushort* yr = Y + ((size_t)node << 6) + r;
#pragma unroll
                for (int ft = 0; ft < 4; ++ft)
                    yr[16 * ft] = (ushort)bf16r(acc[ft][i] * d);
            }
        } else {
#pragma unroll
            for (int i = 0; i < 4; ++i) {
                const int node = n0 + 4 * q + i;
                if (node < n_nodes) {
                    const float d = deg[node];
                    ushort* yr = Y + ((size_t)node << 6) + r;
#pragma unroll
                    for (int ft = 0; ft < 4; ++ft)
                        yr[16 * ft] = (ushort)bf16r(acc[ft][i] * d);
                }
            }
        }
    }
}

// ---------------------------------------------------------------------------
// K2: out[i][:] = deg[i] * sum_e Y[col[e]][:]  — 4 nodes per wave, no
// cross-lane ops. lane = (slot s=lane>>4 -> node, chunk f=lane&15 ->
// features [4f,4f+4)). Each lane owns its node's 16 edge indices (4 dwordx4
// loads), 16 independent dwordx2 row loads, accumulates 4 fp32, stores one
// float4. ~205 MB random full-line gather (each 128B line = one fully-used
// Y row) from L2/LLC — compulsory-traffic floor at ~6.6 TB/s effective.
// ---------------------------------------------------------------------------
__global__ __launch_bounds__(256, 4)
void gcn_gather4(const ushort* __restrict__ Y, const int* __restrict__ rp,
                 const int* __restrict__ col, const float* __restrict__ deg,
                 float* __restrict__ out, int n_nodes)
{
    const int lane   = threadIdx.x & 63;
    const int s      = lane >> 4;
    const int f      = lane & 15;
    const int gwave  = (int)((blockIdx.x * blockDim.x + threadIdx.x) >> 6);
    const int nwaves = (int)((gridDim.x * blockDim.x) >> 6);
    const int ngroups = (n_nodes + 3) >> 2;

    for (int g = gwave; g < ngroups; g += nwaves) {
        const int  n     = g * 4 + s;
        const bool valid = (n < n_nodes);
        const int  rpn   = valid ? rp[n]     : 0;
        const int  rpe   = valid ? rp[n + 1] : 0;
        const int  dcnt  = rpe - rpn;

        const bool ok = !valid || (dcnt == 16 && (rpn & 3) == 0);
        if (__ballot(ok) == ~0ull) {
            int idx[16];
            *(int4*)(idx + 0)  = *(const int4*)(col + rpn + 0);
            *(int4*)(idx + 4)  = *(const int4*)(col + rpn + 4);
            *(int4*)(idx + 8)  = *(const int4*)(col + rpn + 8);
            *(int4*)(idx + 12) = *(const int4*)(col + rpn + 12);

            float a0 = 0.f, a1 = 0.f, a2 = 0.f, a3 = 0.f;
#pragma unroll
            for (int j = 0; j < 16; ++j) {
                const uint2 u = *(const uint2*)(Y + ((size_t)idx[j] << 6) + (f << 2));
                a0 += __uint_as_float(u.x << 16);
                a1 += __uint_as_float(u.x & 0xffff0000u);
                a2 += __uint_as_float(u.y << 16);
                a3 += __uint_as_float(u.y & 0xffff0000u);
            }
            if (valid) {
                const float dn = deg[n];
                float4 v;
                v.x = a0 * dn; v.y = a1 * dn; v.z = a2 * dn; v.w = a3 * dn;
                *(float4*)(out + (size_t)n * D + f * 4) = v;
            }
        } else if (valid) {
            float a0 = 0.f, a1 = 0.f, a2 = 0.f, a3 = 0.f;
            for (int e = rpn; e < rpe; ++e) {
                const int sj = col[e];
                const uint2 u = *(const uint2*)(Y + ((size_t)sj << 6) + (f << 2));
                a0 += __uint_as_float(u.x << 16);
                a1 += __uint_as_float(u.x & 0xffff0000u);
                a2 += __uint_as_float(u.y << 16);
                a3 += __uint_as_float(u.y & 0xffff0000u);
            }
            const float dn = deg[n];
            float4 v;
            v.x = a0 * dn; v.y = a1 * dn; v.z = a2 * dn; v.w = a3 * dn;
            *(float4*)(out + (size_t)n * D + f * 4) = v;
        }
    }
}

// ---------------------------------------------------------------------------
// Fallback (ws too small): fused fp32 kernel.
// ---------------------------------------------------------------------------
static __device__ __forceinline__ float bcast_f(float v, int l) {
    return __uint_as_float(__builtin_amdgcn_readlane(__float_as_uint(v), l));
}

__global__ __launch_bounds__(256, 4)
void gcn_fused_kernel(const float* __restrict__ X, const float* __restrict__ W,
                      const int* __restrict__ rp, const int* __restrict__ col,
                      const float* __restrict__ deg, float* __restrict__ out,
                      int n_nodes)
{
    const int lane   = threadIdx.x & 63;
    const int gwave  = (int)((blockIdx.x * blockDim.x + threadIdx.x) >> 6);
    const int nwaves = (int)((gridDim.x * blockDim.x) >> 6);

    for (int node = gwave; node < n_nodes; node += nwaves) {
        const int start = rp[node];
        const int end   = rp[node + 1];
        const float di  = deg[node];
        float h = 0.f;

        for (int e0 = start; e0 < end; e0 += 64) {
            const int cnt = min(64, end - e0);
            int   s_  = (lane < cnt) ? col[e0 + lane] : 0;
            float nm_ = (lane < cnt) ? di * deg[s_] : 0.f;
            for (int j = 0; j < cnt; ++j) {
                const int   sj = __builtin_amdgcn_readlane(s_, j);
                const float nj = bcast_f(nm_, j);
                h = fmaf(nj, X[(size_t)sj * D + lane], h);
            }
        }

        float c0 = 0.f, c1 = 0.f, c2 = 0.f, c3 = 0.f;
#pragma unroll
        for (int l = 0; l < D; l += 4) {
            c0 = fmaf(bcast_f(h, l + 0), W[(l + 0) * D + lane], c0);
            c1 = fmaf(bcast_f(h, l + 1), W[(l + 1) * D + lane], c1);
            c2 = fmaf(bcast_f(h, l + 2), W[(l + 2) * D + lane], c2);
            c3 = fmaf(bcast_f(h, l + 3), W[(l + 3) * D + lane], c3);
        }
        out[(size_t)node * D + lane] = (c0 + c1) + (c2 + c3);
    }
}

extern "C" void kernel_launch(void* const* d_in, const int* in_sizes, int n_in,
                              void* d_out, int out_size, void* d_ws, size_t ws_size,
                              hipStream_t stream) {
    const float* X   = (const float*)d_in[0];
    const float* W   = (const float*)d_in[1];
    const int*   rp  = (const int*)d_in[2];
    const int*   col = (const int*)d_in[3];
    const float* deg = (const float*)d_in[4];
    float* out = (float*)d_out;

    const int n_nodes = in_sizes[4];   // degrees: one per node
    const size_t y_bytes = (size_t)n_nodes * D * sizeof(ushort);

    if (ws_size >= y_bytes) {
        ushort* Y = (ushort*)d_ws;
        const int nstrips = (n_nodes + 15) / 16;
        // 768 blocks = 3/CU = 3 waves/SIMD; W staged to LDS once per block
        // (round 8 paid 64 scattered vmem + 64 cvt per WAVE for B-fragments).
        gcn_xw_mfma<<<768, 256, 0, stream>>>(X, W, deg, Y, n_nodes, nstrips);
        gcn_gather4<<<2048, 256, 0, stream>>>(Y, rp, col, deg, out, n_nodes);
    } else {
        gcn_fused_kernel<<<1024, 256, 0, stream>>>(X, W, rp, col, deg, out, n_nodes);
    }
}